// Round 3
// baseline (435.544 us; speedup 1.0000x reference)
//
#include <hip/hip_runtime.h>
#include <hip/hip_bf16.h>
#include <stdint.h>

typedef float f32x4 __attribute__((ext_vector_type(4)));
typedef __bf16 v8bf __attribute__((ext_vector_type(8)));
typedef unsigned short u16x8 __attribute__((ext_vector_type(8)));

#define MFMA16 __builtin_amdgcn_mfma_f32_16x16x32_bf16

__device__ __forceinline__ void gload16(const void* g, void* l) {
  auto gp = reinterpret_cast<const __attribute__((address_space(1))) unsigned int*>(
      reinterpret_cast<uintptr_t>(g));
  auto lp = reinterpret_cast<__attribute__((address_space(3))) unsigned int*>(
      reinterpret_cast<uintptr_t>(l));
  __builtin_amdgcn_global_load_lds(gp, lp, 16, 0, 0);
}

// RNE f32 -> bf16 (inputs are finite; no NaN handling needed)
__device__ __forceinline__ unsigned short f2bf(float f) {
  unsigned int u = __builtin_bit_cast(unsigned int, f);
  u += 0x7fffu + ((u >> 16) & 1u);
  return (unsigned short)(u >> 16);
}

// ---------------- cast f32 -> bf16, 8 elems/thread ----------------
__global__ __launch_bounds__(256) void cast_f32_bf16(const float* __restrict__ in,
                                                     unsigned short* __restrict__ out,
                                                     int n8) {
  int i = blockIdx.x * 256 + threadIdx.x;
  if (i >= n8) return;
  f32x4 a = *(const f32x4*)(in + (size_t)i * 8);
  f32x4 b = *(const f32x4*)(in + (size_t)i * 8 + 4);
  u16x8 v;
  v[0] = f2bf(a[0]); v[1] = f2bf(a[1]); v[2] = f2bf(a[2]); v[3] = f2bf(a[3]);
  v[4] = f2bf(b[0]); v[5] = f2bf(b[1]); v[6] = f2bf(b[2]); v[7] = f2bf(b[3]);
  *(u16x8*)(out + (size_t)i * 8) = v;
}

// ---------------- GEMM: C[M,N] = A[M,K] * Bw[N,K]^T (both bf16, row-major,
// K contiguous). 128x128 tile, BK=64, 4 waves (2x2 of 64x64).
// LDS staged via global_load_lds w/ pre-swizzled source (chunk ^= row&7).
// EPI=0: scatter bf16 into QKV [3][B][H][N][64]. EPI=1: fp32 + bias. ----------
template <int EPI>
__global__ __launch_bounds__(256) void gemm_bt(const unsigned short* __restrict__ A,
                                               const unsigned short* __restrict__ Bw,
                                               unsigned short* __restrict__ Cb,
                                               float* __restrict__ Cf,
                                               const float* __restrict__ bias,
                                               int K, int nTilesN) {
  __shared__ __attribute__((aligned(16))) unsigned short As[128 * 64];
  __shared__ __attribute__((aligned(16))) unsigned short Bs[128 * 64];
  const int tid = threadIdx.x, lane = tid & 63, wv = tid >> 6;
  const int wr = wv >> 1, wc = wv & 1;
  const int l15 = lane & 15, lg = lane >> 4;
  const int m0 = (blockIdx.x / nTilesN) * 128;
  const int n0 = (blockIdx.x % nTilesN) * 128;

  f32x4 acc[4][4];
  const f32x4 z = {0.f, 0.f, 0.f, 0.f};
#pragma unroll
  for (int i = 0; i < 4; ++i)
#pragma unroll
    for (int j = 0; j < 4; ++j) acc[i][j] = z;

  // staging lane geometry: 1KB chunk = 8 rows x (8 chunks of 8 bf16).
  // lane l -> local row (l>>3), source 16B-chunk ((l&7) ^ (l>>3)) [swizzle]
  const int jr = lane >> 3;
  const int c8 = (lane & 7) ^ jr;
  const unsigned short* Ag = A + (size_t)(m0 + wv * 32 + jr) * K + c8 * 8;
  const unsigned short* Bg = Bw + (size_t)(n0 + wv * 32 + jr) * K + c8 * 8;

  for (int kk = 0; kk < K; kk += 64) {
#pragma unroll
    for (int q4 = 0; q4 < 4; ++q4) {
      gload16(Ag + (size_t)q4 * 8 * K + kk, As + (wv * 4 + q4) * 512);
      gload16(Bg + (size_t)q4 * 8 * K + kk, Bs + (wv * 4 + q4) * 512);
    }
    __syncthreads();

    v8bf af[2][4], bfr[2][4];
#pragma unroll
    for (int mt = 0; mt < 4; ++mt) {
      const int r = wr * 64 + mt * 16 + l15;
      const int rx = r & 7;
      af[0][mt] = *(const v8bf*)(As + r * 64 + (lg ^ rx) * 8);
      af[1][mt] = *(const v8bf*)(As + r * 64 + ((4 + lg) ^ rx) * 8);
    }
#pragma unroll
    for (int nt = 0; nt < 4; ++nt) {
      const int r = wc * 64 + nt * 16 + l15;
      const int rx = r & 7;
      bfr[0][nt] = *(const v8bf*)(Bs + r * 64 + (lg ^ rx) * 8);
      bfr[1][nt] = *(const v8bf*)(Bs + r * 64 + ((4 + lg) ^ rx) * 8);
    }
#pragma unroll
    for (int mt = 0; mt < 4; ++mt)
#pragma unroll
      for (int nt = 0; nt < 4; ++nt) {
        acc[mt][nt] = MFMA16(af[0][mt], bfr[0][nt], acc[mt][nt], 0, 0, 0);
        acc[mt][nt] = MFMA16(af[1][mt], bfr[1][nt], acc[mt][nt], 0, 0, 0);
      }
    __syncthreads();
  }

#pragma unroll
  for (int mt = 0; mt < 4; ++mt)
#pragma unroll
    for (int nt = 0; nt < 4; ++nt)
#pragma unroll
      for (int r = 0; r < 4; ++r) {
        const int row = m0 + wr * 64 + mt * 16 + lg * 4 + r;
        const int col = n0 + wc * 64 + nt * 16 + l15;
        const float v = acc[mt][nt][r];
        if constexpr (EPI == 0) {
          // QKV scatter: [3][B=4][H=16][N=2048][64]
          const int mat = col >> 10, hc = col & 1023;
          const size_t dst =
              ((size_t)(mat * 64 + (row >> 11) * 16 + (hc >> 6)) * 2048 + (row & 2047)) * 64 +
              (hc & 63);
          Cb[dst] = f2bf(v);
        } else {
          Cf[(size_t)row * 1024 + col] = v + bias[col];
        }
      }
}

// ---------------- flash attention ----------------
// grid (32, 64): x = Q-tile (64 rows), y = b*16+h. 4 waves x 16 Q-rows.
// KVBLK=64. K in swizzled LDS via global_load_lds; V reg-transposed into
// padded LDS [64][72]; P via per-wave padded LDS for the PV A-fragment.
__global__ __launch_bounds__(256) void attn(const unsigned short* __restrict__ qkv,
                                            unsigned short* __restrict__ ao) {
  __shared__ __attribute__((aligned(16))) unsigned short Ks[64 * 64];
  __shared__ __attribute__((aligned(16))) unsigned short Vts[64][72];
  __shared__ __attribute__((aligned(16))) unsigned short Pl[4][16][72];
  const int bh = blockIdx.y;
  const int q0 = blockIdx.x * 64;
  const int tid = threadIdx.x, lane = tid & 63, wv = tid >> 6;
  const int l15 = lane & 15, lg = lane >> 4;
  const size_t NH = (size_t)2048 * 64;
  const unsigned short* Qg = qkv + (size_t)bh * NH;
  const unsigned short* Kg = qkv + (size_t)(64 + bh) * NH;
  const unsigned short* Vg = qkv + (size_t)(128 + bh) * NH;

  // Q fragments held in registers for the whole kernel
  const int qrow = q0 + wv * 16 + l15;
  const v8bf aq0 = *(const v8bf*)(Qg + (size_t)qrow * 64 + lg * 8);
  const v8bf aq1 = *(const v8bf*)(Qg + (size_t)qrow * 64 + 32 + lg * 8);

  const f32x4 z = {0.f, 0.f, 0.f, 0.f};
  float m_r[4], l_r[4];
  f32x4 oacc[4];
#pragma unroll
  for (int r = 0; r < 4; ++r) { m_r[r] = -3.0e38f; l_r[r] = 0.f; }
#pragma unroll
  for (int dt = 0; dt < 4; ++dt) oacc[dt] = z;

  const float sc = 0.125f * 1.4426950408889634f;  // scale * log2(e)
  const int jr = lane >> 3, c8 = (lane & 7) ^ jr; // K staging swizzle
  const int jp = tid & 31, dg = tid >> 5;         // V transpose mapping

  for (int kv = 0; kv < 2048; kv += 64) {
    // --- stage K (swizzled source -> linear LDS) ---
    gload16(Kg + (size_t)(kv + wv * 16 + jr) * 64 + c8 * 8, Ks + (wv * 2) * 512);
    gload16(Kg + (size_t)(kv + wv * 16 + 8 + jr) * 64 + c8 * 8, Ks + (wv * 2 + 1) * 512);
    // --- stage V transposed: Vts[d][j] = V[j][d], rows padded to 72 ---
    {
      u16x8 v0 = *(const u16x8*)(Vg + (size_t)(kv + 2 * jp) * 64 + dg * 8);
      u16x8 v1 = *(const u16x8*)(Vg + (size_t)(kv + 2 * jp + 1) * 64 + dg * 8);
#pragma unroll
      for (int e = 0; e < 8; ++e) {
        unsigned int pk = (unsigned int)v0[e] | ((unsigned int)v1[e] << 16);
        *(unsigned int*)&Vts[dg * 8 + e][2 * jp] = pk;
      }
    }
    __syncthreads();

    // --- S = (Q K^T) * scale, in log2 domain ---
    f32x4 s[4];
#pragma unroll
    for (int ct = 0; ct < 4; ++ct) {
      const int r = ct * 16 + l15, rx = r & 7;
      const v8bf kb0 = *(const v8bf*)(Ks + r * 64 + (lg ^ rx) * 8);
      const v8bf kb1 = *(const v8bf*)(Ks + r * 64 + ((4 + lg) ^ rx) * 8);
      s[ct] = MFMA16(aq0, kb0, z, 0, 0, 0);
      s[ct] = MFMA16(aq1, kb1, s[ct], 0, 0, 0);
    }

    // --- online softmax (rows live in 16-lane groups) ---
    float t[4][4];
#pragma unroll
    for (int ct = 0; ct < 4; ++ct)
#pragma unroll
      for (int r = 0; r < 4; ++r) t[ct][r] = s[ct][r] * sc;
    float mx[4], al[4], ps[4];
#pragma unroll
    for (int r = 0; r < 4; ++r)
      mx[r] = fmaxf(fmaxf(t[0][r], t[1][r]), fmaxf(t[2][r], t[3][r]));
#pragma unroll
    for (int msk = 1; msk < 16; msk <<= 1)
#pragma unroll
      for (int r = 0; r < 4; ++r) mx[r] = fmaxf(mx[r], __shfl_xor(mx[r], msk));
#pragma unroll
    for (int r = 0; r < 4; ++r) {
      const float mn = fmaxf(m_r[r], mx[r]);
      al[r] = exp2f(m_r[r] - mn);
      m_r[r] = mn;
      l_r[r] *= al[r];
    }
#pragma unroll
    for (int dt = 0; dt < 4; ++dt)
#pragma unroll
      for (int r = 0; r < 4; ++r) oacc[dt][r] *= al[r];
    float p[4][4];
#pragma unroll
    for (int ct = 0; ct < 4; ++ct)
#pragma unroll
      for (int r = 0; r < 4; ++r) p[ct][r] = exp2f(t[ct][r] - m_r[r]);
#pragma unroll
    for (int r = 0; r < 4; ++r) ps[r] = (p[0][r] + p[1][r]) + (p[2][r] + p[3][r]);
#pragma unroll
    for (int msk = 1; msk < 16; msk <<= 1)
#pragma unroll
      for (int r = 0; r < 4; ++r) ps[r] += __shfl_xor(ps[r], msk);
#pragma unroll
    for (int r = 0; r < 4; ++r) l_r[r] += ps[r];

    // --- P -> per-wave LDS (relayout C/D -> A fragment) ---
#pragma unroll
    for (int ct = 0; ct < 4; ++ct)
#pragma unroll
      for (int r = 0; r < 4; ++r)
        Pl[wv][lg * 4 + r][ct * 16 + l15] = f2bf(p[ct][r]);

    // --- O += P V ---
    const v8bf pa0 = *(const v8bf*)(&Pl[wv][l15][lg * 8]);
    const v8bf pa1 = *(const v8bf*)(&Pl[wv][l15][32 + lg * 8]);
#pragma unroll
    for (int dt = 0; dt < 4; ++dt) {
      const v8bf vb0 = *(const v8bf*)(&Vts[dt * 16 + l15][lg * 8]);
      const v8bf vb1 = *(const v8bf*)(&Vts[dt * 16 + l15][32 + lg * 8]);
      oacc[dt] = MFMA16(pa0, vb0, oacc[dt], 0, 0, 0);
      oacc[dt] = MFMA16(pa1, vb1, oacc[dt], 0, 0, 0);
    }
    __syncthreads();
  }

  // --- finalize: divide by l, store bf16 to AO [B][N][1024] ---
  const int b = bh >> 4, h = bh & 15;
  float inv[4];
#pragma unroll
  for (int r = 0; r < 4; ++r) inv[r] = 1.0f / l_r[r];
#pragma unroll
  for (int dt = 0; dt < 4; ++dt)
#pragma unroll
    for (int r = 0; r < 4; ++r) {
      const int row = q0 + wv * 16 + lg * 4 + r;
      const int col = h * 64 + dt * 16 + l15;
      ao[((size_t)b * 2048 + row) * 1024 + col] = f2bf(oacc[dt][r] * inv[r]);
    }
}

extern "C" void kernel_launch(void* const* d_in, const int* in_sizes, int n_in,
                              void* d_out, int out_size, void* d_ws, size_t ws_size,
                              hipStream_t stream) {
  (void)in_sizes; (void)n_in; (void)out_size; (void)ws_size;
  const float* x = (const float*)d_in[0];     // [4,2048,1024]
  const float* Wqkv = (const float*)d_in[1];  // [3072,1024]
  const float* Wout = (const float*)d_in[2];  // [1024,1024]
  const float* bout = (const float*)d_in[3];  // [1024]
  float* out = (float*)d_out;                 // [4,2048,1024] fp32

  char* ws = (char*)d_ws;
  unsigned short* Xb  = (unsigned short*)(ws);                         // 16 MB
  unsigned short* Wqb = (unsigned short*)(ws + (size_t)16 * 1048576);  //  6 MB
  unsigned short* Wob = (unsigned short*)(ws + (size_t)22 * 1048576);  //  2 MB
  unsigned short* QKV = (unsigned short*)(ws + (size_t)24 * 1048576);  // 48 MB
  unsigned short* AO  = (unsigned short*)(ws + (size_t)72 * 1048576);  // 16 MB

  cast_f32_bf16<<<4096, 256, 0, stream>>>(x, Xb, 1048576);
  cast_f32_bf16<<<1536, 256, 0, stream>>>(Wqkv, Wqb, 393216);
  cast_f32_bf16<<<512, 256, 0, stream>>>(Wout, Wob, 131072);
  // QKV = Xb[8192,1024] @ Wqb[3072,1024]^T  -> scatter [3][4][16][2048][64]
  gemm_bt<0><<<64 * 24, 256, 0, stream>>>(Xb, Wqb, QKV, nullptr, nullptr, 1024, 24);
  // attention -> AO [4][2048][1024] bf16
  attn<<<dim3(32, 64), 256, 0, stream>>>(QKV, AO);
  // out = AO @ Wob^T + b  -> fp32
  gemm_bt<1><<<64 * 8, 256, 0, stream>>>(AO, Wob, nullptr, out, bout, 1024, 8);
}

// Round 6
// 333.417 us; speedup vs baseline: 1.3063x; 1.3063x over previous
//
#include <hip/hip_runtime.h>
#include <hip/hip_bf16.h>
#include <stdint.h>

typedef float f32x4 __attribute__((ext_vector_type(4)));
typedef __bf16 v8bf __attribute__((ext_vector_type(8)));
typedef __bf16 v4bf __attribute__((ext_vector_type(4)));
typedef unsigned short u16x8 __attribute__((ext_vector_type(8)));

#define MFMA16 __builtin_amdgcn_mfma_f32_16x16x32_bf16

__device__ __forceinline__ void gload16(const void* g, void* l) {
  auto gp = reinterpret_cast<const __attribute__((address_space(1))) unsigned int*>(
      reinterpret_cast<uintptr_t>(g));
  auto lp = reinterpret_cast<__attribute__((address_space(3))) unsigned int*>(
      reinterpret_cast<uintptr_t>(l));
  __builtin_amdgcn_global_load_lds(gp, lp, 16, 0, 0);
}

// RNE f32 -> bf16 (inputs are finite; no NaN handling needed)
__device__ __forceinline__ unsigned short f2bf(float f) {
  unsigned int u = __builtin_bit_cast(unsigned int, f);
  u += 0x7fffu + ((u >> 16) & 1u);
  return (unsigned short)(u >> 16);
}

// ---------------- cast f32 -> bf16, 8 elems/thread ----------------
__global__ __launch_bounds__(256) void cast_f32_bf16(const float* __restrict__ in,
                                                     unsigned short* __restrict__ out,
                                                     int n8) {
  int i = blockIdx.x * 256 + threadIdx.x;
  if (i >= n8) return;
  f32x4 a = *(const f32x4*)(in + (size_t)i * 8);
  f32x4 b = *(const f32x4*)(in + (size_t)i * 8 + 4);
  u16x8 v;
  v[0] = f2bf(a[0]); v[1] = f2bf(a[1]); v[2] = f2bf(a[2]); v[3] = f2bf(a[3]);
  v[4] = f2bf(b[0]); v[5] = f2bf(b[1]); v[6] = f2bf(b[2]); v[7] = f2bf(b[3]);
  *(u16x8*)(out + (size_t)i * 8) = v;
}

// ---------------- GEMM: C[M,N] = A[M,K] * Bw[N,K]^T (both bf16, row-major,
// K contiguous). 128x128 tile, BK=64, 4 waves (2x2 of 64x64).
// LDS staged via global_load_lds w/ pre-swizzled source (chunk ^= row&7).
// EPI=0: scatter bf16 into QKV [3][B][H][N][64]. EPI=1: fp32 + bias. ----------
template <int EPI>
__global__ __launch_bounds__(256) void gemm_bt(const unsigned short* __restrict__ A,
                                               const unsigned short* __restrict__ Bw,
                                               unsigned short* __restrict__ Cb,
                                               float* __restrict__ Cf,
                                               const float* __restrict__ bias,
                                               int K, int nTilesN) {
  __shared__ __attribute__((aligned(16))) unsigned short As[128 * 64];
  __shared__ __attribute__((aligned(16))) unsigned short Bs[128 * 64];
  const int tid = threadIdx.x, lane = tid & 63, wv = tid >> 6;
  const int wr = wv >> 1, wc = wv & 1;
  const int l15 = lane & 15, lg = lane >> 4;
  const int m0 = (blockIdx.x / nTilesN) * 128;
  const int n0 = (blockIdx.x % nTilesN) * 128;

  f32x4 acc[4][4];
  const f32x4 z = {0.f, 0.f, 0.f, 0.f};
#pragma unroll
  for (int i = 0; i < 4; ++i)
#pragma unroll
    for (int j = 0; j < 4; ++j) acc[i][j] = z;

  // staging lane geometry: 1KB chunk = 8 rows x (8 chunks of 8 bf16).
  // lane l -> local row (l>>3), source 16B-chunk ((l&7) ^ (l>>3)) [swizzle]
  const int jr = lane >> 3;
  const int c8 = (lane & 7) ^ jr;
  const unsigned short* Ag = A + (size_t)(m0 + wv * 32 + jr) * K + c8 * 8;
  const unsigned short* Bg = Bw + (size_t)(n0 + wv * 32 + jr) * K + c8 * 8;

  for (int kk = 0; kk < K; kk += 64) {
#pragma unroll
    for (int q4 = 0; q4 < 4; ++q4) {
      gload16(Ag + (size_t)q4 * 8 * K + kk, As + (wv * 4 + q4) * 512);
      gload16(Bg + (size_t)q4 * 8 * K + kk, Bs + (wv * 4 + q4) * 512);
    }
    __syncthreads();

    v8bf af[2][4], bfr[2][4];
#pragma unroll
    for (int mt = 0; mt < 4; ++mt) {
      const int r = wr * 64 + mt * 16 + l15;
      const int rx = r & 7;
      af[0][mt] = *(const v8bf*)(As + r * 64 + (lg ^ rx) * 8);
      af[1][mt] = *(const v8bf*)(As + r * 64 + ((4 + lg) ^ rx) * 8);
    }
#pragma unroll
    for (int nt = 0; nt < 4; ++nt) {
      const int r = wc * 64 + nt * 16 + l15;
      const int rx = r & 7;
      bfr[0][nt] = *(const v8bf*)(Bs + r * 64 + (lg ^ rx) * 8);
      bfr[1][nt] = *(const v8bf*)(Bs + r * 64 + ((4 + lg) ^ rx) * 8);
    }
#pragma unroll
    for (int mt = 0; mt < 4; ++mt)
#pragma unroll
      for (int nt = 0; nt < 4; ++nt) {
        acc[mt][nt] = MFMA16(af[0][mt], bfr[0][nt], acc[mt][nt], 0, 0, 0);
        acc[mt][nt] = MFMA16(af[1][mt], bfr[1][nt], acc[mt][nt], 0, 0, 0);
      }
    __syncthreads();
  }

#pragma unroll
  for (int mt = 0; mt < 4; ++mt)
#pragma unroll
    for (int nt = 0; nt < 4; ++nt)
#pragma unroll
      for (int r = 0; r < 4; ++r) {
        const int row = m0 + wr * 64 + mt * 16 + lg * 4 + r;
        const int col = n0 + wc * 64 + nt * 16 + l15;
        const float v = acc[mt][nt][r];
        if constexpr (EPI == 0) {
          // QKV scatter: [3][B=4][H=16][N=2048][64]
          const int mat = col >> 10, hc = col & 1023;
          const size_t dst =
              ((size_t)(mat * 64 + (row >> 11) * 16 + (hc >> 6)) * 2048 + (row & 2047)) * 64 +
              (hc & 63);
          Cb[dst] = f2bf(v);
        } else {
          Cf[(size_t)row * 1024 + col] = v + bias[col];
        }
      }
}

// ---------------- flash attention (swapped-QK^T, in-lane softmax) ----------------
// grid (32, 64): x = Q-tile (64 rows), y = b*16+h. 4 waves x 16 Q-rows.
// KVBLK=64. S' = mfma(K, Q) puts a full q-row's scores in-lane:
// lane(l15,lg) holds S[q=l15][kv=ct*16+lg*4+r]. Row reduce = 15 in-lane ops +
// shfl_xor(16,32). Defer-max (THR=10 log2) skips O-rescale on most tiles.
// P packed to bf16x4 -> 4 ds_write_b64 into XOR-swizzled Pl, read back as A-frag.
__global__ __launch_bounds__(256) void attn(const unsigned short* __restrict__ qkv,
                                            unsigned short* __restrict__ ao) {
  __shared__ __attribute__((aligned(16))) unsigned short Ks[64 * 64];
  __shared__ __attribute__((aligned(16))) unsigned short Vts[64][72];
  __shared__ __attribute__((aligned(16))) unsigned short Pl[4][16][64];
  const int bh = blockIdx.y;
  const int q0 = blockIdx.x * 64;
  const int tid = threadIdx.x, lane = tid & 63, wv = tid >> 6;
  const int l15 = lane & 15, lg = lane >> 4;
  const int a7 = l15 & 7;
  const size_t NH = (size_t)2048 * 64;
  const unsigned short* Qg = qkv + (size_t)bh * NH;
  const unsigned short* Kg = qkv + (size_t)(64 + bh) * NH;
  const unsigned short* Vg = qkv + (size_t)(128 + bh) * NH;

  // Q fragments held in registers for the whole kernel (B-operand now)
  const int qrow = q0 + wv * 16 + l15;
  const v8bf aq0 = *(const v8bf*)(Qg + (size_t)qrow * 64 + lg * 8);
  const v8bf aq1 = *(const v8bf*)(Qg + (size_t)qrow * 64 + 32 + lg * 8);

  const f32x4 z = {0.f, 0.f, 0.f, 0.f};
  float m_r = -3.0e38f, l_r = 0.f;  // per-lane: q-row = l15 (in raw-score units)
  f32x4 oacc[4];
#pragma unroll
  for (int dt = 0; dt < 4; ++dt) oacc[dt] = z;

  const float sc = 0.125f * 1.4426950408889634f;  // scale * log2(e)
  const float THR = 55.4f;                        // 10 log2-units / sc
  const int jr = lane >> 3, c8 = (lane & 7) ^ jr; // K staging swizzle
  const int jp = tid & 31, dg = tid >> 5;         // V transpose mapping

  for (int kv = 0; kv < 2048; kv += 64) {
    // --- stage K (swizzled source -> linear LDS) ---
    gload16(Kg + (size_t)(kv + wv * 16 + jr) * 64 + c8 * 8, Ks + (wv * 2) * 512);
    gload16(Kg + (size_t)(kv + wv * 16 + 8 + jr) * 64 + c8 * 8, Ks + (wv * 2 + 1) * 512);
    // --- stage V transposed: Vts[d][j] = V[j][d], rows padded to 72 ---
    {
      u16x8 v0 = *(const u16x8*)(Vg + (size_t)(kv + 2 * jp) * 64 + dg * 8);
      u16x8 v1 = *(const u16x8*)(Vg + (size_t)(kv + 2 * jp + 1) * 64 + dg * 8);
#pragma unroll
      for (int e = 0; e < 8; ++e) {
        unsigned int pk = (unsigned int)v0[e] | ((unsigned int)v1[e] << 16);
        *(unsigned int*)&Vts[dg * 8 + e][2 * jp] = pk;
      }
    }
    __syncthreads();

    // --- S' = K Q^T: lane holds S[q=l15][kv_sub = ct*16 + lg*4 + r] ---
    f32x4 s[4];
#pragma unroll
    for (int ct = 0; ct < 4; ++ct) {
      const int r = ct * 16 + l15, rx = r & 7;
      const v8bf kb0 = *(const v8bf*)(Ks + r * 64 + (lg ^ rx) * 8);
      const v8bf kb1 = *(const v8bf*)(Ks + r * 64 + ((4 + lg) ^ rx) * 8);
      s[ct] = MFMA16(kb0, aq0, z, 0, 0, 0);
      s[ct] = MFMA16(kb1, aq1, s[ct], 0, 0, 0);
    }

    // --- row max: in-lane tree (16 vals) + 2 shuffles (raw-score units) ---
    float m01 = fmaxf(fmaxf(s[0][0], s[0][1]), fmaxf(s[0][2], s[0][3]));
    float m23 = fmaxf(fmaxf(s[1][0], s[1][1]), fmaxf(s[1][2], s[1][3]));
    float m45 = fmaxf(fmaxf(s[2][0], s[2][1]), fmaxf(s[2][2], s[2][3]));
    float m67 = fmaxf(fmaxf(s[3][0], s[3][1]), fmaxf(s[3][2], s[3][3]));
    float mx = fmaxf(fmaxf(m01, m23), fmaxf(m45, m67));
    mx = fmaxf(mx, __shfl_xor(mx, 16));
    mx = fmaxf(mx, __shfl_xor(mx, 32));

    // --- defer-max: rescale only when the running max grew past THR ---
    if (__any(mx > m_r + THR)) {
      const float mn = fmaxf(m_r, mx);
      const float al = __builtin_amdgcn_exp2f((m_r - mn) * sc);
      m_r = mn;
      l_r *= al;
#pragma unroll
      for (int r = 0; r < 4; ++r) {
        const float a = __shfl(al, lg * 4 + r);  // al for q-row = lg*4+r
#pragma unroll
        for (int dt = 0; dt < 4; ++dt) oacc[dt][r] *= a;
      }
    }

    // --- P = exp2(fma(s, sc, -m*sc)), in-lane sum + 2 shuffles ---
    const float ms = m_r * sc;
    float p[4][4];
#pragma unroll
    for (int ct = 0; ct < 4; ++ct)
#pragma unroll
      for (int r = 0; r < 4; ++r)
        p[ct][r] = __builtin_amdgcn_exp2f(fmaf(s[ct][r], sc, -ms));
    float ps = ((p[0][0] + p[0][1]) + (p[0][2] + p[0][3])) +
               ((p[1][0] + p[1][1]) + (p[1][2] + p[1][3])) +
               ((p[2][0] + p[2][1]) + (p[2][2] + p[2][3])) +
               ((p[3][0] + p[3][1]) + (p[3][2] + p[3][3]));
    ps += __shfl_xor(ps, 16);
    ps += __shfl_xor(ps, 32);
    l_r += ps;

    // --- pack P -> Pl[q][kv] (bf16x4, XOR-swizzled 16B chunks) ---
#pragma unroll
    for (int ct = 0; ct < 4; ++ct) {
      v4bf pk;
      pk[0] = (__bf16)p[ct][0]; pk[1] = (__bf16)p[ct][1];
      pk[2] = (__bf16)p[ct][2]; pk[3] = (__bf16)p[ct][3];
      const int cst = ct * 2 + (lg >> 1);  // 16B-chunk index of kv0=ct*16+lg*4
      *(v4bf*)(&Pl[wv][l15][((cst ^ a7) << 3) + ((lg & 1) << 2)]) = pk;
    }

    // --- O += P V (A-frag read mirrors the swizzle) ---
    const v8bf pa0 = *(const v8bf*)(&Pl[wv][l15][(lg ^ a7) * 8]);
    const v8bf pa1 = *(const v8bf*)(&Pl[wv][l15][((4 + lg) ^ a7) * 8]);
#pragma unroll
    for (int dt = 0; dt < 4; ++dt) {
      const v8bf vb0 = *(const v8bf*)(&Vts[dt * 16 + l15][lg * 8]);
      const v8bf vb1 = *(const v8bf*)(&Vts[dt * 16 + l15][32 + lg * 8]);
      oacc[dt] = MFMA16(pa0, vb0, oacc[dt], 0, 0, 0);
      oacc[dt] = MFMA16(pa1, vb1, oacc[dt], 0, 0, 0);
    }
    __syncthreads();
  }

  // --- finalize: divide by l (fetched from the l15-lane holding this q-row) ---
  const int b = bh >> 4, h = bh & 15;
  const float linv = 1.0f / l_r;
  float invr[4];
#pragma unroll
  for (int r = 0; r < 4; ++r) invr[r] = __shfl(linv, lg * 4 + r);
#pragma unroll
  for (int dt = 0; dt < 4; ++dt)
#pragma unroll
    for (int r = 0; r < 4; ++r) {
      const int row = q0 + wv * 16 + lg * 4 + r;
      const int col = h * 64 + dt * 16 + l15;
      ao[((size_t)b * 2048 + row) * 1024 + col] = f2bf(oacc[dt][r] * invr[r]);
    }
}

extern "C" void kernel_launch(void* const* d_in, const int* in_sizes, int n_in,
                              void* d_out, int out_size, void* d_ws, size_t ws_size,
                              hipStream_t stream) {
  (void)in_sizes; (void)n_in; (void)out_size; (void)ws_size;
  const float* x = (const float*)d_in[0];     // [4,2048,1024]
  const float* Wqkv = (const float*)d_in[1];  // [3072,1024]
  const float* Wout = (const float*)d_in[2];  // [1024,1024]
  const float* bout = (const float*)d_in[3];  // [1024]
  float* out = (float*)d_out;                 // [4,2048,1024] fp32

  char* ws = (char*)d_ws;
  unsigned short* Xb  = (unsigned short*)(ws);                         // 16 MB
  unsigned short* Wqb = (unsigned short*)(ws + (size_t)16 * 1048576);  //  6 MB
  unsigned short* Wob = (unsigned short*)(ws + (size_t)22 * 1048576);  //  2 MB
  unsigned short* QKV = (unsigned short*)(ws + (size_t)24 * 1048576);  // 48 MB
  unsigned short* AO  = (unsigned short*)(ws + (size_t)72 * 1048576);  // 16 MB

  cast_f32_bf16<<<4096, 256, 0, stream>>>(x, Xb, 1048576);
  cast_f32_bf16<<<1536, 256, 0, stream>>>(Wqkv, Wqb, 393216);
  cast_f32_bf16<<<512, 256, 0, stream>>>(Wout, Wob, 131072);
  // QKV = Xb[8192,1024] @ Wqb[3072,1024]^T  -> scatter [3][4][16][2048][64]
  gemm_bt<0><<<64 * 24, 256, 0, stream>>>(Xb, Wqb, QKV, nullptr, nullptr, 1024, 24);
  // attention -> AO [4][2048][1024] bf16
  attn<<<dim3(32, 64), 256, 0, stream>>>(QKV, AO);
  // out = AO @ Wob^T + b  -> fp32
  gemm_bt<1><<<64 * 8, 256, 0, stream>>>(AO, Wob, nullptr, out, bout, 1024, 8);
}

// Round 12
// 325.723 us; speedup vs baseline: 1.3372x; 1.0236x over previous
//
#include <hip/hip_runtime.h>
#include <hip/hip_bf16.h>
#include <stdint.h>

typedef float f32x4 __attribute__((ext_vector_type(4)));
typedef __bf16 v8bf __attribute__((ext_vector_type(8)));
typedef __bf16 v4bf __attribute__((ext_vector_type(4)));
typedef unsigned short u16x8 __attribute__((ext_vector_type(8)));

#define MFMA16 __builtin_amdgcn_mfma_f32_16x16x32_bf16

__device__ __forceinline__ void gload16(const void* g, void* l) {
  auto gp = reinterpret_cast<const __attribute__((address_space(1))) unsigned int*>(
      reinterpret_cast<uintptr_t>(g));
  auto lp = reinterpret_cast<__attribute__((address_space(3))) unsigned int*>(
      reinterpret_cast<uintptr_t>(l));
  __builtin_amdgcn_global_load_lds(gp, lp, 16, 0, 0);
}

// RNE f32 -> bf16 (inputs are finite; no NaN handling needed)
__device__ __forceinline__ unsigned short f2bf(float f) {
  unsigned int u = __builtin_bit_cast(unsigned int, f);
  u += 0x7fffu + ((u >> 16) & 1u);
  return (unsigned short)(u >> 16);
}

// ---------------- cast f32 -> bf16, 8 elems/thread ----------------
__global__ __launch_bounds__(256) void cast_f32_bf16(const float* __restrict__ in,
                                                     unsigned short* __restrict__ out,
                                                     int n8) {
  int i = blockIdx.x * 256 + threadIdx.x;
  if (i >= n8) return;
  f32x4 a = *(const f32x4*)(in + (size_t)i * 8);
  f32x4 b = *(const f32x4*)(in + (size_t)i * 8 + 4);
  u16x8 v;
  v[0] = f2bf(a[0]); v[1] = f2bf(a[1]); v[2] = f2bf(a[2]); v[3] = f2bf(a[3]);
  v[4] = f2bf(b[0]); v[5] = f2bf(b[1]); v[6] = f2bf(b[2]); v[7] = f2bf(b[3]);
  *(u16x8*)(out + (size_t)i * 8) = v;
}

// ---------------- GEMM: C[M,N] = A[M,K] * Bw[N,K]^T (both bf16, row-major,
// K contiguous). 128x128 tile, BK=64, 4 waves (2x2 of 64x64).
// LDS staged via global_load_lds w/ pre-swizzled source (chunk ^= row&7).
// XCD-aware bijective blockIdx swizzle (grid % 8 == 0 for both uses).
// EPI=0: scatter bf16 into QKV [3][B][H][N][64]. EPI=1: fp32 + bias. ----------
template <int EPI>
__global__ __launch_bounds__(256) void gemm_bt(const unsigned short* __restrict__ A,
                                               const unsigned short* __restrict__ Bw,
                                               unsigned short* __restrict__ Cb,
                                               float* __restrict__ Cf,
                                               const float* __restrict__ bias,
                                               int K, int nTilesN) {
  __shared__ __attribute__((aligned(16))) unsigned short As[128 * 64];
  __shared__ __attribute__((aligned(16))) unsigned short Bs[128 * 64];
  const int tid = threadIdx.x, lane = tid & 63, wv = tid >> 6;
  const int wr = wv >> 1, wc = wv & 1;
  const int l15 = lane & 15, lg = lane >> 4;
  // XCD swizzle: 8 XCDs, grid divisible by 8 -> bijective chunked remap
  const int nwg = gridDim.x;
  int bid = blockIdx.x;
  bid = (bid & 7) * (nwg >> 3) + (bid >> 3);
  const int m0 = (bid / nTilesN) * 128;
  const int n0 = (bid % nTilesN) * 128;

  f32x4 acc[4][4];
  const f32x4 z = {0.f, 0.f, 0.f, 0.f};
#pragma unroll
  for (int i = 0; i < 4; ++i)
#pragma unroll
    for (int j = 0; j < 4; ++j) acc[i][j] = z;

  // staging lane geometry: 1KB chunk = 8 rows x (8 chunks of 8 bf16).
  // lane l -> local row (l>>3), source 16B-chunk ((l&7) ^ (l>>3)) [swizzle]
  const int jr = lane >> 3;
  const int c8 = (lane & 7) ^ jr;
  const unsigned short* Ag = A + (size_t)(m0 + wv * 32 + jr) * K + c8 * 8;
  const unsigned short* Bg = Bw + (size_t)(n0 + wv * 32 + jr) * K + c8 * 8;

  for (int kk = 0; kk < K; kk += 64) {
#pragma unroll
    for (int q4 = 0; q4 < 4; ++q4) {
      gload16(Ag + (size_t)q4 * 8 * K + kk, As + (wv * 4 + q4) * 512);
      gload16(Bg + (size_t)q4 * 8 * K + kk, Bs + (wv * 4 + q4) * 512);
    }
    __syncthreads();

    v8bf af[2][4], bfr[2][4];
#pragma unroll
    for (int mt = 0; mt < 4; ++mt) {
      const int r = wr * 64 + mt * 16 + l15;
      const int rx = r & 7;
      af[0][mt] = *(const v8bf*)(As + r * 64 + (lg ^ rx) * 8);
      af[1][mt] = *(const v8bf*)(As + r * 64 + ((4 + lg) ^ rx) * 8);
    }
#pragma unroll
    for (int nt = 0; nt < 4; ++nt) {
      const int r = wc * 64 + nt * 16 + l15;
      const int rx = r & 7;
      bfr[0][nt] = *(const v8bf*)(Bs + r * 64 + (lg ^ rx) * 8);
      bfr[1][nt] = *(const v8bf*)(Bs + r * 64 + ((4 + lg) ^ rx) * 8);
    }
#pragma unroll
    for (int mt = 0; mt < 4; ++mt)
#pragma unroll
      for (int nt = 0; nt < 4; ++nt) {
        acc[mt][nt] = MFMA16(af[0][mt], bfr[0][nt], acc[mt][nt], 0, 0, 0);
        acc[mt][nt] = MFMA16(af[1][mt], bfr[1][nt], acc[mt][nt], 0, 0, 0);
      }
    __syncthreads();
  }

#pragma unroll
  for (int mt = 0; mt < 4; ++mt)
#pragma unroll
    for (int nt = 0; nt < 4; ++nt)
#pragma unroll
      for (int r = 0; r < 4; ++r) {
        const int row = m0 + wr * 64 + mt * 16 + lg * 4 + r;
        const int col = n0 + wc * 64 + nt * 16 + l15;
        const float v = acc[mt][nt][r];
        if constexpr (EPI == 0) {
          // QKV scatter: [3][B=4][H=16][N=2048][64]
          const int mat = col >> 10, hc = col & 1023;
          const size_t dst =
              ((size_t)(mat * 64 + (row >> 11) * 16 + (hc >> 6)) * 2048 + (row & 2047)) * 64 +
              (hc & 63);
          Cb[dst] = f2bf(v);
        } else {
          Cf[(size_t)row * 1024 + col] = v + bias[col];
        }
      }
}

// ---------------- flash attention (swapped-QK^T, QBLK=128) ----------------
// grid (16, 64): x = Q-tile (128 rows), y = b*16+h. 4 waves x 32 Q-rows
// (2 groups of 16). KVBLK=64. Staging (K swizzled gload_lds, V reg-transpose)
// is PER TILE and now amortized over 2x the Q-rows; K-frags read once and
// reused for both groups; Pl (per-wave) reused serially by g0 then g1
// (in-order DS within a wave -> no extra barrier).
__global__ __launch_bounds__(256) void attn(const unsigned short* __restrict__ qkv,
                                            unsigned short* __restrict__ ao) {
  __shared__ __attribute__((aligned(16))) unsigned short Ks[64 * 64];
  __shared__ __attribute__((aligned(16))) unsigned short Vts[64][72];
  __shared__ __attribute__((aligned(16))) unsigned short Pl[4][16][64];
  const int bh = blockIdx.y;
  const int q0 = blockIdx.x * 128;
  const int tid = threadIdx.x, lane = tid & 63, wv = tid >> 6;
  const int l15 = lane & 15, lg = lane >> 4;
  const int a7 = l15 & 7;
  const size_t NH = (size_t)2048 * 64;
  const unsigned short* Qg = qkv + (size_t)bh * NH;
  const unsigned short* Kg = qkv + (size_t)(64 + bh) * NH;
  const unsigned short* Vg = qkv + (size_t)(128 + bh) * NH;

  // Q fragments: 2 groups x 2 k-halves, held for the whole kernel
  const int qrow = q0 + wv * 32 + l15;  // group 0; group 1 = +16
  v8bf aq[2][2];
  aq[0][0] = *(const v8bf*)(Qg + (size_t)qrow * 64 + lg * 8);
  aq[0][1] = *(const v8bf*)(Qg + (size_t)qrow * 64 + 32 + lg * 8);
  aq[1][0] = *(const v8bf*)(Qg + (size_t)(qrow + 16) * 64 + lg * 8);
  aq[1][1] = *(const v8bf*)(Qg + (size_t)(qrow + 16) * 64 + 32 + lg * 8);

  const f32x4 z = {0.f, 0.f, 0.f, 0.f};
  float m_r[2] = {-3.0e38f, -3.0e38f}, l_r[2] = {0.f, 0.f};
  f32x4 oacc[2][4];
#pragma unroll
  for (int g = 0; g < 2; ++g)
#pragma unroll
    for (int dt = 0; dt < 4; ++dt) oacc[g][dt] = z;

  const float sc = 0.125f * 1.4426950408889634f;  // scale * log2(e)
  const float THR = 55.4f;                        // 10 log2-units / sc
  const int jr = lane >> 3, c8 = (lane & 7) ^ jr; // K staging swizzle
  const int jp = tid & 31, dg = tid >> 5;         // V transpose mapping

  for (int kv = 0; kv < 2048; kv += 64) {
    // --- stage K (swizzled source -> linear LDS) ---
    gload16(Kg + (size_t)(kv + wv * 16 + jr) * 64 + c8 * 8, Ks + (wv * 2) * 512);
    gload16(Kg + (size_t)(kv + wv * 16 + 8 + jr) * 64 + c8 * 8, Ks + (wv * 2 + 1) * 512);
    // --- stage V transposed: Vts[d][j] = V[j][d], rows padded to 72 ---
    {
      u16x8 v0 = *(const u16x8*)(Vg + (size_t)(kv + 2 * jp) * 64 + dg * 8);
      u16x8 v1 = *(const u16x8*)(Vg + (size_t)(kv + 2 * jp + 1) * 64 + dg * 8);
#pragma unroll
      for (int e = 0; e < 8; ++e) {
        unsigned int pk = (unsigned int)v0[e] | ((unsigned int)v1[e] << 16);
        *(unsigned int*)&Vts[dg * 8 + e][2 * jp] = pk;
      }
    }
    __syncthreads();

    // --- S' = K Q^T for BOTH groups; K-frags read once ---
    f32x4 s[2][4];
#pragma unroll
    for (int ct = 0; ct < 4; ++ct) {
      const int r = ct * 16 + l15, rx = r & 7;
      const v8bf kb0 = *(const v8bf*)(Ks + r * 64 + (lg ^ rx) * 8);
      const v8bf kb1 = *(const v8bf*)(Ks + r * 64 + ((4 + lg) ^ rx) * 8);
      s[0][ct] = MFMA16(kb0, aq[0][0], z, 0, 0, 0);
      s[0][ct] = MFMA16(kb1, aq[0][1], s[0][ct], 0, 0, 0);
      s[1][ct] = MFMA16(kb0, aq[1][0], z, 0, 0, 0);
      s[1][ct] = MFMA16(kb1, aq[1][1], s[1][ct], 0, 0, 0);
    }

#pragma unroll
    for (int g = 0; g < 2; ++g) {
      // --- row max: in-lane tree (16 vals) + 2 shuffles ---
      float m01 = fmaxf(fmaxf(s[g][0][0], s[g][0][1]), fmaxf(s[g][0][2], s[g][0][3]));
      float m23 = fmaxf(fmaxf(s[g][1][0], s[g][1][1]), fmaxf(s[g][1][2], s[g][1][3]));
      float m45 = fmaxf(fmaxf(s[g][2][0], s[g][2][1]), fmaxf(s[g][2][2], s[g][2][3]));
      float m67 = fmaxf(fmaxf(s[g][3][0], s[g][3][1]), fmaxf(s[g][3][2], s[g][3][3]));
      float mx = fmaxf(fmaxf(m01, m23), fmaxf(m45, m67));
      mx = fmaxf(mx, __shfl_xor(mx, 16));
      mx = fmaxf(mx, __shfl_xor(mx, 32));

      // --- defer-max: rescale only when the running max grew past THR ---
      if (__any(mx > m_r[g] + THR)) {
        const float mn = fmaxf(m_r[g], mx);
        const float al = __builtin_amdgcn_exp2f((m_r[g] - mn) * sc);
        m_r[g] = mn;
        l_r[g] *= al;
#pragma unroll
        for (int r = 0; r < 4; ++r) {
          const float a = __shfl(al, lg * 4 + r);  // al for q-row = lg*4+r
#pragma unroll
          for (int dt = 0; dt < 4; ++dt) oacc[g][dt][r] *= a;
        }
      }

      // --- P = exp2(fma(s, sc, -m*sc)) in place; in-lane sum + 2 shuffles ---
      const float ms = m_r[g] * sc;
      float p[4][4];
#pragma unroll
      for (int ct = 0; ct < 4; ++ct)
#pragma unroll
        for (int r = 0; r < 4; ++r)
          p[ct][r] = __builtin_amdgcn_exp2f(fmaf(s[g][ct][r], sc, -ms));
      float ps = ((p[0][0] + p[0][1]) + (p[0][2] + p[0][3])) +
                 ((p[1][0] + p[1][1]) + (p[1][2] + p[1][3])) +
                 ((p[2][0] + p[2][1]) + (p[2][2] + p[2][3])) +
                 ((p[3][0] + p[3][1]) + (p[3][2] + p[3][3]));
      ps += __shfl_xor(ps, 16);
      ps += __shfl_xor(ps, 32);
      l_r[g] += ps;

      // --- pack P -> Pl[q][kv] (bf16x4, XOR-swizzled 16B chunks) ---
#pragma unroll
      for (int ct = 0; ct < 4; ++ct) {
        v4bf pk;
        pk[0] = (__bf16)p[ct][0]; pk[1] = (__bf16)p[ct][1];
        pk[2] = (__bf16)p[ct][2]; pk[3] = (__bf16)p[ct][3];
        const int cst = ct * 2 + (lg >> 1);  // 16B-chunk index of kv0=ct*16+lg*4
        *(v4bf*)(&Pl[wv][l15][((cst ^ a7) << 3) + ((lg & 1) << 2)]) = pk;
      }

      // --- O += P V (A-frag read mirrors the swizzle; per-wave Pl, no barrier) ---
      const v8bf pa0 = *(const v8bf*)(&Pl[wv][l15][(lg ^ a7) * 8]);
      const v8bf pa1 = *(const v8bf*)(&Pl[wv][l15][((4 + lg) ^ a7) * 8]);
#pragma unroll
      for (int dt = 0; dt < 4; ++dt) {
        const v8bf vb0 = *(const v8bf*)(&Vts[dt * 16 + l15][lg * 8]);
        const v8bf vb1 = *(const v8bf*)(&Vts[dt * 16 + l15][32 + lg * 8]);
        oacc[g][dt] = MFMA16(pa0, vb0, oacc[g][dt], 0, 0, 0);
        oacc[g][dt] = MFMA16(pa1, vb1, oacc[g][dt], 0, 0, 0);
      }
    }
    __syncthreads();
  }

  // --- finalize: divide by l (fetched from the lane holding this q-row) ---
  const int b = bh >> 4, h = bh & 15;
#pragma unroll
  for (int g = 0; g < 2; ++g) {
    const float linv = 1.0f / l_r[g];
    float invr[4];
#pragma unroll
    for (int r = 0; r < 4; ++r) invr[r] = __shfl(linv, lg * 4 + r);
#pragma unroll
    for (int dt = 0; dt < 4; ++dt)
#pragma unroll
      for (int r = 0; r < 4; ++r) {
        const int row = q0 + wv * 32 + g * 16 + lg * 4 + r;
        const int col = h * 64 + dt * 16 + l15;
        ao[((size_t)b * 2048 + row) * 1024 + col] = f2bf(oacc[g][dt][r] * invr[r]);
      }
  }
}

extern "C" void kernel_launch(void* const* d_in, const int* in_sizes, int n_in,
                              void* d_out, int out_size, void* d_ws, size_t ws_size,
                              hipStream_t stream) {
  (void)in_sizes; (void)n_in; (void)out_size; (void)ws_size;
  const float* x = (const float*)d_in[0];     // [4,2048,1024]
  const float* Wqkv = (const float*)d_in[1];  // [3072,1024]
  const float* Wout = (const float*)d_in[2];  // [1024,1024]
  const float* bout = (const float*)d_in[3];  // [1024]
  float* out = (float*)d_out;                 // [4,2048,1024] fp32

  char* ws = (char*)d_ws;
  unsigned short* Xb  = (unsigned short*)(ws);                         // 16 MB
  unsigned short* Wqb = (unsigned short*)(ws + (size_t)16 * 1048576);  //  6 MB
  unsigned short* Wob = (unsigned short*)(ws + (size_t)22 * 1048576);  //  2 MB
  unsigned short* QKV = (unsigned short*)(ws + (size_t)24 * 1048576);  // 48 MB
  unsigned short* AO  = (unsigned short*)(ws + (size_t)72 * 1048576);  // 16 MB

  cast_f32_bf16<<<4096, 256, 0, stream>>>(x, Xb, 1048576);
  cast_f32_bf16<<<1536, 256, 0, stream>>>(Wqkv, Wqb, 393216);
  cast_f32_bf16<<<512, 256, 0, stream>>>(Wout, Wob, 131072);
  // QKV = Xb[8192,1024] @ Wqb[3072,1024]^T  -> scatter [3][4][16][2048][64]
  gemm_bt<0><<<64 * 24, 256, 0, stream>>>(Xb, Wqb, QKV, nullptr, nullptr, 1024, 24);
  // attention -> AO [4][2048][1024] bf16  (QBLK=128)
  attn<<<dim3(16, 64), 256, 0, stream>>>(QKV, AO);
  // out = AO @ Wob^T + b  -> fp32
  gemm_bt<1><<<64 * 8, 256, 0, stream>>>(AO, Wob, nullptr, out, bout, 1024, 8);
}